// Round 4
// baseline (37279.013 us; speedup 1.0000x reference)
//
#include <hip/hip_runtime.h>
#include <stdint.h>

// ODE-LSTM (PersonActivityModel): B=256,T=128,IN=64,H=512,C=11, fp32 in/out.
//
// u-space RK4 folding: M = W2^T W1^T, d = b2·W1^T:
//   u1 = h·W1^T+b1; D_i = tanh(u_i)·M; u2=u1+.5dt(D1+d); u3=u1+.5dt(D2+d);
//   u4=u1+dt(D3+d); SM=D1+2D2+2D3+D4; u_next=u1+(dt/6)SM+dt·d;
//   S=t1+2t2+2t3+t4 over 3 unfolds; h += (dt/6)(S_tot·W2^T)+3dt·b2.
// out = h·(Wc·Wo)^T + (Wc·bo + bc) deferred; gates z = [h|x]·[Whh|Wih]^T.
//
// 16 clusters (16 batches) x 8 CUs (64-col slab) = 128 WGs. Per CU: M-slab
// B-frags in VGPRs, W1/W2 slabs in LDS (128 KB), gates slab streamed from L2.
// Activation exchange: row-major [m][512] fp16 cluster buffers in L2 (ping-pong
// by phase parity) + monotonic-flag agent-scope barriers.
// ROUND-4 FIX: publisher now writes row-major [m][512] to match the stager
// (round 3 wrote slab-major s*1024+m*64+colw -> scrambled A-fragments).

#define H_  512
#define B_  256
#define T_  128
#define IN_ 64
#define NC_ 11

typedef _Float16 h8v __attribute__((ext_vector_type(8)));
typedef float    f4v __attribute__((ext_vector_type(4)));

__device__ __forceinline__ float fsigm(float x) { return 1.0f / (1.0f + __expf(-x)); }
__device__ __forceinline__ float ftanh(float x) { return 1.0f - 2.0f / (1.0f + __expf(2.0f * x)); }

// ---------------- prep kernels (fp32 weights -> fp16 MFMA B-fragment tables) ----------------

// Mtmp[k][n] = sum_m W2[m][k] * W1[n][m]   [M = W2^T W1^T]
__global__ void prep_M(const float* __restrict__ W1, const float* __restrict__ W2,
                       float* __restrict__ Mtmp) {
  __shared__ float w1s[8][512];
  int tid = threadIdx.x;
  int n0 = blockIdx.x * 8;
  for (int i = tid; i < 8 * 512; i += 256) {
    int nn = i >> 9, m = i & 511;
    w1s[nn][m] = W1[(n0 + nn) * 512 + m];
  }
  __syncthreads();
  float acc0[8] = {0,0,0,0,0,0,0,0}, acc1[8] = {0,0,0,0,0,0,0,0};
  for (int m = 0; m < 512; ++m) {
    float a = W2[m * 512 + tid];
    float b = W2[m * 512 + 256 + tid];
#pragma unroll
    for (int j = 0; j < 8; ++j) { acc0[j] += a * w1s[j][m]; acc1[j] += b * w1s[j][m]; }
  }
  for (int j = 0; j < 8; ++j) {
    Mtmp[(size_t)tid * 512 + n0 + j]         = acc0[j];
    Mtmp[(size_t)(tid + 256) * 512 + n0 + j] = acc1[j];
  }
}

__global__ void prep_small(const float* __restrict__ W1, const float* __restrict__ b2,
                           const float* __restrict__ Wc, const float* __restrict__ Wo,
                           const float* __restrict__ bo, const float* __restrict__ bc,
                           float* __restrict__ dvec, float* __restrict__ Wco,
                           float* __restrict__ bprime) {
  __shared__ float wcs[NC_ * 512];
  int tid = threadIdx.x;
  if (blockIdx.x == 0) {
    for (int n = tid; n < 512; n += 256) {
      float acc = 0.f;
      for (int m = 0; m < 512; ++m) acc += b2[m] * W1[n * 512 + m];
      dvec[n] = acc;
    }
  } else if (blockIdx.x == 1) {
    if (tid < NC_) {
      float acc = bc[tid];
      for (int m = 0; m < 512; ++m) acc += Wc[tid * 512 + m] * bo[m];
      bprime[tid] = acc;
    }
  } else {
    for (int i = tid; i < NC_ * 512; i += 256) wcs[i] = Wc[i];
    __syncthreads();
    int h = (blockIdx.x - 2) * 256 + tid;
    float acc[NC_];
#pragma unroll
    for (int c = 0; c < NC_; ++c) acc[c] = 0.f;
    for (int m = 0; m < 512; ++m) {
      float wo = Wo[m * 512 + h];
#pragma unroll
      for (int c = 0; c < NC_; ++c) acc[c] += wo * wcs[c * 512 + m];
    }
    for (int c = 0; c < NC_; ++c) Wco[c * 512 + h] = acc[c];
  }
}

// B-frag tables: frag fb = 64 lanes x 8 halfs (1KB). B[k][n]:
// lane holds n = tile*16+(lane&15), k = kc*32+((lane>>4)&3)*8+j.
// Gates: fb = (g*32 + tile)*18 + kc (K=576: k<512 Whh, k>=512 Wih).
__global__ void prep_wtilde(const float* __restrict__ Whh, const float* __restrict__ Wih,
                            _Float16* __restrict__ Wtil) {
  int gidx = blockIdx.x * 256 + threadIdx.x;  // 2304 fb * 64 lanes
  int lane = gidx & 63, fb = gidx >> 6;
  int kc = fb % 18; int t2 = fb / 18;
  int t = t2 & 31, g = t2 >> 5;
  int n = g * 512 + t * 16 + (lane & 15);
  int k = kc * 32 + ((lane >> 4) & 3) * 8;
  _Float16 vals[8];
  if (k < 512) {
#pragma unroll
    for (int j = 0; j < 8; ++j) vals[j] = (_Float16)Whh[(size_t)n * 512 + k + j];
  } else {
#pragma unroll
    for (int j = 0; j < 8; ++j) vals[j] = (_Float16)Wih[(size_t)n * 64 + (k - 512) + j];
  }
  *(h8v*)(Wtil + (size_t)fb * 512 + lane * 8) = *(h8v*)vals;
}

// W (512x512): fb = tile*16 + kc;  B[k][n] = W[n][k]
__global__ void prep_fragW(const float* __restrict__ W, _Float16* __restrict__ dst) {
  int gidx = blockIdx.x * 256 + threadIdx.x;  // 512 fb * 64 lanes
  int lane = gidx & 63, fb = gidx >> 6;
  int t = fb >> 4, kc = fb & 15;
  int n = t * 16 + (lane & 15);
  int k = kc * 32 + ((lane >> 4) & 3) * 8;
  _Float16 vals[8];
#pragma unroll
  for (int j = 0; j < 8; ++j) vals[j] = (_Float16)W[(size_t)n * 512 + k + j];
  *(h8v*)(dst + (size_t)fb * 512 + lane * 8) = *(h8v*)vals;
}

// M table: B[k][n] = Mtmp[k][n]
__global__ void prep_fragM(const float* __restrict__ Mtmp, _Float16* __restrict__ dst) {
  int gidx = blockIdx.x * 256 + threadIdx.x;
  int lane = gidx & 63, fb = gidx >> 6;
  int t = fb >> 4, kc = fb & 15;
  int n = t * 16 + (lane & 15);
  int k = kc * 32 + ((lane >> 4) & 3) * 8;
  _Float16 vals[8];
#pragma unroll
  for (int j = 0; j < 8; ++j) vals[j] = (_Float16)Mtmp[(size_t)(k + j) * 512 + n];
  *(h8v*)(dst + (size_t)fb * 512 + lane * 8) = *(h8v*)vals;
}

// ---------------- recurrence ----------------

// cross-CU barrier + stage full 16x512 fp16 activation (row-major Xc[m][512])
// into fragment-layout LDS AF ([kc][lane][8] halfs, conflict-free ds_read_b128).
__device__ __forceinline__ void xbar_stage(int* __restrict__ flags,
                                           const _Float16* __restrict__ Xc,
                                           _Float16* __restrict__ AF,
                                           int c, int s, int phase) {
  __syncthreads();
  __threadfence();          // publish stores visible agent-wide
  __syncthreads();
  int tid = threadIdx.x;
  if (tid == 0)
    __hip_atomic_store(&flags[(c * 8 + s) * 16], phase, __ATOMIC_RELEASE, __HIP_MEMORY_SCOPE_AGENT);
  if (tid < 8)
    while (__hip_atomic_load(&flags[(c * 8 + tid) * 16], __ATOMIC_ACQUIRE, __HIP_MEMORY_SCOPE_AGENT) < phase)
      __builtin_amdgcn_s_sleep(1);
  __syncthreads();
  __threadfence();          // acquire side: invalidate stale lines
  {
    int l = tid & 63, kcb = tid >> 6;
#pragma unroll
    for (int i = 0; i < 4; ++i) {
      int kc = kcb * 4 + i;
      h8v v = *(const h8v*)(Xc + (l & 15) * 512 + kc * 32 + (l >> 4) * 8);
      *(h8v*)(AF + kc * 512 + l * 8) = v;
    }
  }
  __syncthreads();
}

__device__ __forceinline__ f4v mm_lds(const _Float16* __restrict__ AF,
                                      const _Float16* __restrict__ Ws,
                                      int w, int lane) {
  f4v e = {0, 0, 0, 0}, o = {0, 0, 0, 0};
  const h8v* a = (const h8v*)AF;
  const h8v* b = (const h8v*)Ws;
#pragma unroll
  for (int kc = 0; kc < 16; kc += 2) {
    e = __builtin_amdgcn_mfma_f32_16x16x32_f16(a[kc * 64 + lane],       b[(w * 16 + kc) * 64 + lane],     e, 0, 0, 0);
    o = __builtin_amdgcn_mfma_f32_16x16x32_f16(a[(kc + 1) * 64 + lane], b[(w * 16 + kc + 1) * 64 + lane], o, 0, 0, 0);
  }
  return e + o;
}

__device__ __forceinline__ f4v mm_reg(const _Float16* __restrict__ AF,
                                      const h8v* __restrict__ mreg, int lane) {
  f4v e = {0, 0, 0, 0}, o = {0, 0, 0, 0};
  const h8v* a = (const h8v*)AF;
#pragma unroll
  for (int kc = 0; kc < 16; kc += 2) {
    e = __builtin_amdgcn_mfma_f32_16x16x32_f16(a[kc * 64 + lane],       mreg[kc],     e, 0, 0, 0);
    o = __builtin_amdgcn_mfma_f32_16x16x32_f16(a[(kc + 1) * 64 + lane], mreg[kc + 1], o, 0, 0, 0);
  }
  return e + o;
}

__launch_bounds__(256, 1)
__global__ void recur(const float* __restrict__ x,
                      const float* __restrict__ tin,
                      const float* __restrict__ bih,
                      const float* __restrict__ bhh,
                      const float* __restrict__ b1g,
                      const float* __restrict__ b2g,
                      const _Float16* __restrict__ Wtil,
                      const _Float16* __restrict__ W1T,
                      const _Float16* __restrict__ W2T,
                      const _Float16* __restrict__ MF,
                      const float* __restrict__ dvec,
                      _Float16* __restrict__ Hsave,
                      _Float16* __restrict__ Xchg,
                      int* __restrict__ flags) {
  const int blk = blockIdx.x, c = blk & 15, s = blk >> 4;   // cluster, slab
  const int tid = threadIdx.x, w = tid >> 6, lane = tid & 63;
  const int lm = lane & 15, quad = lane >> 4;
  const int col = s * 64 + w * 16 + lm;                     // global hidden col

  __shared__ __align__(16) _Float16 W1s[4 * 16 * 512];      // 64 KB
  __shared__ __align__(16) _Float16 W2s[4 * 16 * 512];      // 64 KB
  __shared__ __align__(16) _Float16 AF[16 * 512];           // 16 KB frag-layout

  // stage W1/W2 slabs (64 contiguous frags each, base s*32768 halfs)
  {
    const h8v* g1 = (const h8v*)(W1T + (size_t)s * 32768);
    const h8v* g2 = (const h8v*)(W2T + (size_t)s * 32768);
    h8v* l1 = (h8v*)W1s; h8v* l2 = (h8v*)W2s;
    for (int i = tid; i < 4096; i += 256) { l1[i] = g1[i]; l2[i] = g2[i]; }
  }
  // M slab B-frags into VGPRs (tile 4s+w)
  h8v mreg[16];
  {
    const h8v* gm = (const h8v*)(MF + ((size_t)(4 * s + w) * 16) * 512);
#pragma unroll
    for (int kc = 0; kc < 16; ++kc) mreg[kc] = gm[kc * 64 + lane];
  }
  // zero AF (h0 = 0)
  for (int i = tid; i < 1024; i += 256) ((uint4*)AF)[i] = make_uint4(0, 0, 0, 0);

  const float zb0 = bih[col] + bhh[col];
  const float zb1 = bih[512 + col] + bhh[512 + col];
  const float zb2 = bih[1024 + col] + bhh[1024 + col];
  const float zb3 = bih[1536 + col] + bhh[1536 + col];
  const float b1r = b1g[col], dvr = dvec[col], b2r = b2g[col];

  float c_[4] = {0, 0, 0, 0}, h_[4] = {0, 0, 0, 0};
  float u1a[4], SSa[4], SMa[4];
  int phase = 0;
  // ROW-MAJOR publish: element (m = quad*4+r, col) at m*512 + col
  const size_t pubrow = (size_t)(quad * 4) * 512 + col;
  __syncthreads();

  for (int ts = 0; ts < T_; ++ts) {
    float dt_[4];
#pragma unroll
    for (int r = 0; r < 4; ++r)
      dt_[r] = tin[(c * 16 + quad * 4 + r) * T_ + ts] * (1.0f / 3.0f);

    // ---- P1: gates z = [h|x]·Wtil^T (K=576; B streamed from L2) ----
    {
      f4v z0 = {0,0,0,0}, z1 = {0,0,0,0}, z2 = {0,0,0,0}, z3 = {0,0,0,0};
      const h8v* a = (const h8v*)AF;
      const h8v* wt = (const h8v*)Wtil;
      const int tb = 4 * s + w;
#pragma unroll
      for (int kc = 0; kc < 16; ++kc) {
        h8v av = a[kc * 64 + lane];
        z0 = __builtin_amdgcn_mfma_f32_16x16x32_f16(av, wt[(size_t)((0 * 32 + tb) * 18 + kc) * 64 + lane], z0, 0, 0, 0);
        z1 = __builtin_amdgcn_mfma_f32_16x16x32_f16(av, wt[(size_t)((1 * 32 + tb) * 18 + kc) * 64 + lane], z1, 0, 0, 0);
        z2 = __builtin_amdgcn_mfma_f32_16x16x32_f16(av, wt[(size_t)((2 * 32 + tb) * 18 + kc) * 64 + lane], z2, 0, 0, 0);
        z3 = __builtin_amdgcn_mfma_f32_16x16x32_f16(av, wt[(size_t)((3 * 32 + tb) * 18 + kc) * 64 + lane], z3, 0, 0, 0);
      }
      const float* xr = x + ((size_t)(c * 16 + lm) * T_ + ts) * IN_ + quad * 8;
#pragma unroll
      for (int kx = 0; kx < 2; ++kx) {
        float4 f0 = *(const float4*)(xr + kx * 32);
        float4 f1 = *(const float4*)(xr + kx * 32 + 4);
        h8v av;
        av[0] = (_Float16)f0.x; av[1] = (_Float16)f0.y; av[2] = (_Float16)f0.z; av[3] = (_Float16)f0.w;
        av[4] = (_Float16)f1.x; av[5] = (_Float16)f1.y; av[6] = (_Float16)f1.z; av[7] = (_Float16)f1.w;
        int kc = 16 + kx;
        z0 = __builtin_amdgcn_mfma_f32_16x16x32_f16(av, wt[(size_t)((0 * 32 + tb) * 18 + kc) * 64 + lane], z0, 0, 0, 0);
        z1 = __builtin_amdgcn_mfma_f32_16x16x32_f16(av, wt[(size_t)((1 * 32 + tb) * 18 + kc) * 64 + lane], z1, 0, 0, 0);
        z2 = __builtin_amdgcn_mfma_f32_16x16x32_f16(av, wt[(size_t)((2 * 32 + tb) * 18 + kc) * 64 + lane], z2, 0, 0, 0);
        z3 = __builtin_amdgcn_mfma_f32_16x16x32_f16(av, wt[(size_t)((3 * 32 + tb) * 18 + kc) * 64 + lane], z3, 0, 0, 0);
      }
      ++phase;
      _Float16* dst = Xchg + ((size_t)((phase & 1) * 16 + c)) * 8192 + pubrow;
#pragma unroll
      for (int r = 0; r < 4; ++r) {
        float zi = z0[r] + zb0, zf = z1[r] + zb1, zg = z2[r] + zb2, zo = z3[r] + zb3;
        float cv = fsigm(zf) * c_[r] + fsigm(zi) * ftanh(zg);
        c_[r] = cv;
        h_[r] = fsigm(zo) * ftanh(cv);
        dst[r * 512] = (_Float16)h_[r];
      }
    }
    xbar_stage(flags, Xchg + ((size_t)((phase & 1) * 16 + c)) * 8192, AF, c, s, phase);

    // ---- P2: u1 = h·W1^T + b1 ----
    {
      f4v D = mm_lds(AF, W1s, w, lane);
      ++phase;
      _Float16* dst = Xchg + ((size_t)((phase & 1) * 16 + c)) * 8192 + pubrow;
#pragma unroll
      for (int r = 0; r < 4; ++r) {
        float uv = D[r] + b1r;
        u1a[r] = uv;
        float t1v = ftanh(uv);
        SSa[r] = t1v;
        dst[r * 512] = (_Float16)t1v;
      }
    }
    xbar_stage(flags, Xchg + ((size_t)((phase & 1) * 16 + c)) * 8192, AF, c, s, phase);

    // ---- 3 RK4 unfolds in u-space (M in VGPRs) ----
#pragma unroll 1
    for (int uf = 0; uf < 3; ++uf) {
      {
        f4v D = mm_reg(AF, mreg, lane);
        ++phase;
        _Float16* dst = Xchg + ((size_t)((phase & 1) * 16 + c)) * 8192 + pubrow;
#pragma unroll
        for (int r = 0; r < 4; ++r) {
          float Dv = D[r];
          float u2 = u1a[r] + 0.5f * dt_[r] * (Dv + dvr);
          SMa[r] = Dv;
          float t2v = ftanh(u2);
          SSa[r] += 2.0f * t2v;
          dst[r * 512] = (_Float16)t2v;
        }
      }
      xbar_stage(flags, Xchg + ((size_t)((phase & 1) * 16 + c)) * 8192, AF, c, s, phase);

      {
        f4v D = mm_reg(AF, mreg, lane);
        ++phase;
        _Float16* dst = Xchg + ((size_t)((phase & 1) * 16 + c)) * 8192 + pubrow;
#pragma unroll
        for (int r = 0; r < 4; ++r) {
          float Dv = D[r];
          float u3 = u1a[r] + 0.5f * dt_[r] * (Dv + dvr);
          SMa[r] += 2.0f * Dv;
          float t3v = ftanh(u3);
          SSa[r] += 2.0f * t3v;
          dst[r * 512] = (_Float16)t3v;
        }
      }
      xbar_stage(flags, Xchg + ((size_t)((phase & 1) * 16 + c)) * 8192, AF, c, s, phase);

      {
        f4v D = mm_reg(AF, mreg, lane);
        ++phase;
        _Float16* dst = Xchg + ((size_t)((phase & 1) * 16 + c)) * 8192 + pubrow;
#pragma unroll
        for (int r = 0; r < 4; ++r) {
          float Dv = D[r];
          float u4 = u1a[r] + dt_[r] * (Dv + dvr);
          SMa[r] += 2.0f * Dv;
          float t4v = ftanh(u4);
          SSa[r] += t4v;
          dst[r * 512] = (uf < 2) ? (_Float16)t4v : (_Float16)SSa[r];
        }
      }
      xbar_stage(flags, Xchg + ((size_t)((phase & 1) * 16 + c)) * 8192, AF, c, s, phase);

      if (uf < 2) {
        f4v D = mm_reg(AF, mreg, lane);
        ++phase;
        _Float16* dst = Xchg + ((size_t)((phase & 1) * 16 + c)) * 8192 + pubrow;
#pragma unroll
        for (int r = 0; r < 4; ++r) {
          float Dv = D[r];
          SMa[r] += Dv;
          float un = u1a[r] + (dt_[r] * (1.0f / 6.0f)) * SMa[r] + dt_[r] * dvr;
          u1a[r] = un;
          float t1v = ftanh(un);
          SSa[r] += t1v;
          dst[r * 512] = (_Float16)t1v;
        }
        xbar_stage(flags, Xchg + ((size_t)((phase & 1) * 16 + c)) * 8192, AF, c, s, phase);
      }
    }

    // ---- P_h: h += (dt/6)·(S_tot·W2^T) + 3dt·b2 ; publish h + Hsave ----
    {
      f4v D = mm_lds(AF, W2s, w, lane);
      ++phase;
      _Float16* dst = Xchg + ((size_t)((phase & 1) * 16 + c)) * 8192 + pubrow;
#pragma unroll
      for (int r = 0; r < 4; ++r) {
        h_[r] += (dt_[r] * (1.0f / 6.0f)) * D[r] + (3.0f * dt_[r]) * b2r;
        _Float16 hv = (_Float16)h_[r];
        dst[r * 512] = hv;
        Hsave[((size_t)(ts + 1) * B_ + c * 16 + quad * 4 + r) * H_ + col] = hv;
      }
    }
    xbar_stage(flags, Xchg + ((size_t)((phase & 1) * 16 + c)) * 8192, AF, c, s, phase);
  }
}

// ---------------- final projection: out = h·Wco^T + bprime ----------------
__global__ void final_out(const _Float16* __restrict__ Hsave,
                          const float* __restrict__ Wco,
                          const float* __restrict__ bprime,
                          float* __restrict__ out) {
  __shared__ float wcs[NC_][520];
  int tid = threadIdx.x;
  for (int i = tid; i < NC_ * 512; i += 256) wcs[i >> 9][i & 511] = Wco[i];
  __syncthreads();
  int r0 = blockIdx.x * 64;
  int rl = tid >> 4, cc = tid & 15;
  for (int pass = 0; pass < 4; ++pass) {
    int row = r0 + pass * 16 + rl;        // row = b*T + t
    int b = row >> 7, t = row & 127;
    const _Float16* hrow = Hsave + ((size_t)(t + 1) * B_ + b) * H_;
    if (cc < NC_) {
      float acc = 0.f;
      for (int k8 = 0; k8 < 64; ++k8) {
        h8v hv = *(const h8v*)(hrow + k8 * 8);
#pragma unroll
        for (int j = 0; j < 8; ++j) acc += (float)hv[j] * wcs[cc][k8 * 8 + j];
      }
      out[(size_t)row * NC_ + cc] = acc + bprime[cc];
    }
  }
}

extern "C" void kernel_launch(void* const* d_in, const int* in_sizes, int n_in,
                              void* d_out, int out_size, void* d_ws, size_t ws_size,
                              hipStream_t stream) {
  (void)in_sizes; (void)n_in; (void)out_size; (void)ws_size;
  const float* x   = (const float*)d_in[0];
  const float* tin = (const float*)d_in[1];
  const float* Wih = (const float*)d_in[2];
  const float* Whh = (const float*)d_in[3];
  const float* bih = (const float*)d_in[4];
  const float* bhh = (const float*)d_in[5];
  const float* W1  = (const float*)d_in[6];
  const float* b1  = (const float*)d_in[7];
  const float* W2  = (const float*)d_in[8];
  const float* b2  = (const float*)d_in[9];
  const float* Wo  = (const float*)d_in[10];
  const float* bo  = (const float*)d_in[11];
  const float* Wc  = (const float*)d_in[12];
  const float* bc  = (const float*)d_in[13];

  char* ws = (char*)d_ws;
  size_t off = 0;
  auto alloc = [&](size_t bytes) -> void* {
    void* p = ws + off;
    off = (off + bytes + 1023) & ~(size_t)1023;
    return p;
  };
  _Float16* Wtil  = (_Float16*)alloc((size_t)2304 * 512 * 2);
  _Float16* W1T   = (_Float16*)alloc((size_t)512 * 512 * 2);
  _Float16* W2T   = (_Float16*)alloc((size_t)512 * 512 * 2);
  _Float16* MF    = (_Float16*)alloc((size_t)512 * 512 * 2);
  float*    Mtmp  = (float*)alloc((size_t)512 * 512 * 4);
  float*    dvec  = (float*)alloc(512 * 4);
  float*    WcoF  = (float*)alloc((size_t)NC_ * 512 * 4);
  float*    bprim = (float*)alloc(64);
  _Float16* Hsave = (_Float16*)alloc((size_t)(T_ + 1) * B_ * H_ * 2);
  _Float16* Xchg  = (_Float16*)alloc((size_t)2 * 16 * 8192 * 2);
  int*      flags = (int*)alloc(16 * 8 * 16 * 4);

  hipMemsetAsync(flags, 0, 16 * 8 * 16 * 4, stream);

  prep_M<<<64, 256, 0, stream>>>(W1, W2, Mtmp);
  prep_small<<<4, 256, 0, stream>>>(W1, b2, Wc, Wo, bo, bc, dvec, WcoF, bprim);
  prep_wtilde<<<576, 256, 0, stream>>>(Whh, Wih, Wtil);
  prep_fragW<<<128, 256, 0, stream>>>(W1, W1T);
  prep_fragW<<<128, 256, 0, stream>>>(W2, W2T);
  prep_fragM<<<128, 256, 0, stream>>>(Mtmp, MF);
  recur<<<128, 256, 0, stream>>>(x, tin, bih, bhh, b1, b2, Wtil, W1T, W2T, MF,
                                 dvec, Hsave, Xchg, flags);
  final_out<<<512, 256, 0, stream>>>(Hsave, WcoF, bprim, (float*)d_out);
}

// Round 5
// 5056.715 us; speedup vs baseline: 7.3722x; 7.3722x over previous
//
#include <hip/hip_runtime.h>
#include <stdint.h>

// ODE-LSTM (PersonActivityModel): B=256,T=128,IN=64,H=512,C=11, fp32 in/out.
//
// u-space RK4 folding: M = W2^T W1^T, d = b2·W1^T:
//   u1 = h·W1^T+b1; D_i = tanh(u_i)·M; u2=u1+.5dt(D1+d); u3=u1+.5dt(D2+d);
//   u4=u1+dt(D3+d); SM=D1+2D2+2D3+D4; u_next=u1+(dt/6)SM+dt·d;
//   S=t1+2t2+2t3+t4 over 3 unfolds; h += (dt/6)(S_tot·W2^T)+3dt·b2.
// out = h·(Wc·Wo)^T + (Wc·bo + bc) deferred; gates z = [h|x]·[Whh|Wih]^T.
//
// 16 clusters (16 batches) x 8 CUs (64-col slab) = 128 WGs. Per CU: M-slab
// B-frags in VGPRs, W1/W2 slabs in LDS (128 KB), gates slab streamed from L2.
// ROUND-5: fence-free exchange. All Xchg data + barrier counters use RELAXED
// AGENT-scope atomics only (sc0+sc1 -> LLC-coherent, device-wide, no
// buffer_wbl2/inv cache flushes — round 4's 500 MB/dispatch HBM writeback came
// from __threadfence()). Release = s_waitcnt(0)+syncthreads before counter add;
// acquire = relaxed poll + control dependency (LLC serializes data<counter).

#define H_  512
#define B_  256
#define T_  128
#define IN_ 64
#define NC_ 11
#define LD_ 520   // padded LDS row stride (halfs); 16B-aligned rows, spreads banks

typedef _Float16 h8v __attribute__((ext_vector_type(8)));
typedef float    f4v __attribute__((ext_vector_type(4)));
typedef unsigned long long ull;

__device__ __forceinline__ float fsigm(float x) { return 1.0f / (1.0f + __expf(-x)); }
__device__ __forceinline__ float ftanh(float x) { return 1.0f - 2.0f / (1.0f + __expf(2.0f * x)); }

// ---------------- prep kernels (fp32 weights -> fp16 MFMA B-fragment tables) ----------------

__global__ void prep_M(const float* __restrict__ W1, const float* __restrict__ W2,
                       float* __restrict__ Mtmp) {
  __shared__ float w1s[8][512];
  int tid = threadIdx.x;
  int n0 = blockIdx.x * 8;
  for (int i = tid; i < 8 * 512; i += 256) {
    int nn = i >> 9, m = i & 511;
    w1s[nn][m] = W1[(n0 + nn) * 512 + m];
  }
  __syncthreads();
  float acc0[8] = {0,0,0,0,0,0,0,0}, acc1[8] = {0,0,0,0,0,0,0,0};
  for (int m = 0; m < 512; ++m) {
    float a = W2[m * 512 + tid];
    float b = W2[m * 512 + 256 + tid];
#pragma unroll
    for (int j = 0; j < 8; ++j) { acc0[j] += a * w1s[j][m]; acc1[j] += b * w1s[j][m]; }
  }
  for (int j = 0; j < 8; ++j) {
    Mtmp[(size_t)tid * 512 + n0 + j]         = acc0[j];
    Mtmp[(size_t)(tid + 256) * 512 + n0 + j] = acc1[j];
  }
}

__global__ void prep_small(const float* __restrict__ W1, const float* __restrict__ b2,
                           const float* __restrict__ Wc, const float* __restrict__ Wo,
                           const float* __restrict__ bo, const float* __restrict__ bc,
                           float* __restrict__ dvec, float* __restrict__ Wco,
                           float* __restrict__ bprime) {
  __shared__ float wcs[NC_ * 512];
  int tid = threadIdx.x;
  if (blockIdx.x == 0) {
    for (int n = tid; n < 512; n += 256) {
      float acc = 0.f;
      for (int m = 0; m < 512; ++m) acc += b2[m] * W1[n * 512 + m];
      dvec[n] = acc;
    }
  } else if (blockIdx.x == 1) {
    if (tid < NC_) {
      float acc = bc[tid];
      for (int m = 0; m < 512; ++m) acc += Wc[tid * 512 + m] * bo[m];
      bprime[tid] = acc;
    }
  } else {
    for (int i = tid; i < NC_ * 512; i += 256) wcs[i] = Wc[i];
    __syncthreads();
    int h = (blockIdx.x - 2) * 256 + tid;
    float acc[NC_];
#pragma unroll
    for (int c = 0; c < NC_; ++c) acc[c] = 0.f;
    for (int m = 0; m < 512; ++m) {
      float wo = Wo[m * 512 + h];
#pragma unroll
      for (int c = 0; c < NC_; ++c) acc[c] += wo * wcs[c * 512 + m];
    }
    for (int c = 0; c < NC_; ++c) Wco[c * 512 + h] = acc[c];
  }
}

// B-frag tables: frag fb = 64 lanes x 8 halfs (1KB). B[k][n]:
// lane holds n = tile*16+(lane&15), k = kc*32+((lane>>4)&3)*8+j.
__global__ void prep_wtilde(const float* __restrict__ Whh, const float* __restrict__ Wih,
                            _Float16* __restrict__ Wtil) {
  int gidx = blockIdx.x * 256 + threadIdx.x;  // 2304 fb * 64 lanes
  int lane = gidx & 63, fb = gidx >> 6;
  int kc = fb % 18; int t2 = fb / 18;
  int t = t2 & 31, g = t2 >> 5;
  int n = g * 512 + t * 16 + (lane & 15);
  int k = kc * 32 + ((lane >> 4) & 3) * 8;
  _Float16 vals[8];
  if (k < 512) {
#pragma unroll
    for (int j = 0; j < 8; ++j) vals[j] = (_Float16)Whh[(size_t)n * 512 + k + j];
  } else {
#pragma unroll
    for (int j = 0; j < 8; ++j) vals[j] = (_Float16)Wih[(size_t)n * 64 + (k - 512) + j];
  }
  *(h8v*)(Wtil + (size_t)fb * 512 + lane * 8) = *(h8v*)vals;
}

__global__ void prep_fragW(const float* __restrict__ W, _Float16* __restrict__ dst) {
  int gidx = blockIdx.x * 256 + threadIdx.x;  // 512 fb * 64 lanes
  int lane = gidx & 63, fb = gidx >> 6;
  int t = fb >> 4, kc = fb & 15;
  int n = t * 16 + (lane & 15);
  int k = kc * 32 + ((lane >> 4) & 3) * 8;
  _Float16 vals[8];
#pragma unroll
  for (int j = 0; j < 8; ++j) vals[j] = (_Float16)W[(size_t)n * 512 + k + j];
  *(h8v*)(dst + (size_t)fb * 512 + lane * 8) = *(h8v*)vals;
}

__global__ void prep_fragM(const float* __restrict__ Mtmp, _Float16* __restrict__ dst) {
  int gidx = blockIdx.x * 256 + threadIdx.x;
  int lane = gidx & 63, fb = gidx >> 6;
  int t = fb >> 4, kc = fb & 15;
  int n = t * 16 + (lane & 15);
  int k = kc * 32 + ((lane >> 4) & 3) * 8;
  _Float16 vals[8];
#pragma unroll
  for (int j = 0; j < 8; ++j) vals[j] = (_Float16)Mtmp[(size_t)(k + j) * 512 + n];
  *(h8v*)(dst + (size_t)fb * 512 + lane * 8) = *(h8v*)vals;
}

// ---------------- recurrence ----------------

// Exchange after each phase. ACT holds the full 16x512 activation (row-major,
// stride LD_). Epilogue already wrote THIS slab's 64 cols into ACT.
// 1 ull atomic store out, 8 ull atomic loads in, per thread. Xb = ull[16][128].
__device__ __forceinline__ void phase_exchange(int* __restrict__ cnt,
                                               ull* __restrict__ Xb,
                                               _Float16* __restrict__ ACT,
                                               int s, int target) {
  const int tid = threadIdx.x;
  __syncthreads();                                   // self-slab ACT writes done
  {
    int m = tid >> 4, ch = tid & 15;
    ull v = *(const ull*)(ACT + m * LD_ + s * 64 + ch * 4);
    __hip_atomic_store(Xb + m * 128 + s * 16 + ch, v,
                       __ATOMIC_RELAXED, __HIP_MEMORY_SCOPE_AGENT);
  }
  __builtin_amdgcn_s_waitcnt(0);                     // publish stores at LLC
  __syncthreads();                                   // all waves drained
  if (tid == 0)
    __hip_atomic_fetch_add(cnt, 1, __ATOMIC_RELAXED, __HIP_MEMORY_SCOPE_AGENT);
  int v;
  do {
    v = __hip_atomic_load(cnt, __ATOMIC_RELAXED, __HIP_MEMORY_SCOPE_AGENT);
    if (v < target) __builtin_amdgcn_s_sleep(2);
  } while (v < target);
  __asm__ volatile("" ::: "memory");
  ull tv[8];
#pragma unroll
  for (int i = 0; i < 8; ++i) {
    int idx = i * 256 + tid;
    int os = idx >> 8, r = idx & 255, m = r >> 4, ch = r & 15;
    tv[i] = __hip_atomic_load(Xb + m * 128 + os * 16 + ch,
                              __ATOMIC_RELAXED, __HIP_MEMORY_SCOPE_AGENT);
  }
#pragma unroll
  for (int i = 0; i < 8; ++i) {
    int idx = i * 256 + tid;
    int os = idx >> 8, r = idx & 255, m = r >> 4, ch = r & 15;
    *(ull*)(ACT + m * LD_ + os * 64 + ch * 4) = tv[i];
  }
  __syncthreads();                                   // ACT fully staged
}

// One 16x512 @ 512x64 slab phase. A: LDS row-major ACT (stride LD_).
// B from LDS table (W1s/W2s, tiles w*16..): D row=quad*4+r, col=s*64+w*16+lm.
__device__ __forceinline__ f4v mm_lds(const _Float16* __restrict__ ACT,
                                      const _Float16* __restrict__ Ws,
                                      int w, int lane) {
  f4v e = {0,0,0,0}, o = {0,0,0,0};
  const _Float16* arow = ACT + (lane & 15) * LD_ + (lane >> 4) * 8;
  const h8v* b = (const h8v*)Ws;
#pragma unroll
  for (int kc = 0; kc < 16; kc += 2) {
    e = __builtin_amdgcn_mfma_f32_16x16x32_f16(*(const h8v*)(arow + kc * 32),
                                               b[(w * 16 + kc) * 64 + lane], e, 0, 0, 0);
    o = __builtin_amdgcn_mfma_f32_16x16x32_f16(*(const h8v*)(arow + (kc + 1) * 32),
                                               b[(w * 16 + kc + 1) * 64 + lane], o, 0, 0, 0);
  }
  return e + o;
}

__device__ __forceinline__ f4v mm_reg(const _Float16* __restrict__ ACT,
                                      const h8v* __restrict__ mreg, int lane) {
  f4v e = {0,0,0,0}, o = {0,0,0,0};
  const _Float16* arow = ACT + (lane & 15) * LD_ + (lane >> 4) * 8;
#pragma unroll
  for (int kc = 0; kc < 16; kc += 2) {
    e = __builtin_amdgcn_mfma_f32_16x16x32_f16(*(const h8v*)(arow + kc * 32),
                                               mreg[kc], e, 0, 0, 0);
    o = __builtin_amdgcn_mfma_f32_16x16x32_f16(*(const h8v*)(arow + (kc + 1) * 32),
                                               mreg[kc + 1], o, 0, 0, 0);
  }
  return e + o;
}

__launch_bounds__(256, 1)
__global__ void recur(const float* __restrict__ x,
                      const float* __restrict__ tin,
                      const float* __restrict__ bih,
                      const float* __restrict__ bhh,
                      const float* __restrict__ b1g,
                      const float* __restrict__ b2g,
                      const _Float16* __restrict__ Wtil,
                      const _Float16* __restrict__ W1T,
                      const _Float16* __restrict__ W2T,
                      const _Float16* __restrict__ MF,
                      const float* __restrict__ dvec,
                      _Float16* __restrict__ Hsave,
                      ull* __restrict__ Xchg,
                      int* __restrict__ flags) {
  const int blk = blockIdx.x, c = blk & 15, s = blk >> 4;   // cluster, slab
  const int tid = threadIdx.x, w = tid >> 6, lane = tid & 63;
  const int lm = lane & 15, quad = lane >> 4;
  const int col = s * 64 + w * 16 + lm;                     // global hidden col

  __shared__ __align__(16) _Float16 W1s[4 * 16 * 512];      // 64 KB
  __shared__ __align__(16) _Float16 W2s[4 * 16 * 512];      // 64 KB
  __shared__ __align__(16) _Float16 ACT[16 * LD_];          // 16.25 KB row-major

  {
    const h8v* g1 = (const h8v*)(W1T + (size_t)s * 32768);
    const h8v* g2 = (const h8v*)(W2T + (size_t)s * 32768);
    h8v* l1 = (h8v*)W1s; h8v* l2 = (h8v*)W2s;
    for (int i = tid; i < 4096; i += 256) { l1[i] = g1[i]; l2[i] = g2[i]; }
  }
  h8v mreg[16];
  {
    const h8v* gm = (const h8v*)(MF + ((size_t)(4 * s + w) * 16) * 512);
#pragma unroll
    for (int kc = 0; kc < 16; ++kc) mreg[kc] = gm[kc * 64 + lane];
  }
  for (int i = tid; i < 16 * LD_; i += 256) ACT[i] = (_Float16)0.f;

  const float zb0 = bih[col] + bhh[col];
  const float zb1 = bih[512 + col] + bhh[512 + col];
  const float zb2 = bih[1024 + col] + bhh[1024 + col];
  const float zb3 = bih[1536 + col] + bhh[1536 + col];
  const float b1r = b1g[col], dvr = dvec[col], b2r = b2g[col];

  float c_[4] = {0,0,0,0}, h_[4] = {0,0,0,0};
  float u1a[4], SSa[4], SMa[4];
  int phase = 0;
  int* cnt = flags + c * 32;
  __syncthreads();

  for (int ts = 0; ts < T_; ++ts) {
    float dt_[4];
#pragma unroll
    for (int r = 0; r < 4; ++r)
      dt_[r] = tin[(c * 16 + quad * 4 + r) * T_ + ts] * (1.0f / 3.0f);

    // ---- P1: gates z = [h|x]·Wtil^T (K=576; B streamed from L2) ----
    {
      f4v z0 = {0,0,0,0}, z1 = {0,0,0,0}, z2 = {0,0,0,0}, z3 = {0,0,0,0};
      const _Float16* arow = ACT + lm * LD_ + quad * 8;
      const h8v* wt = (const h8v*)Wtil;
      const int tb = 4 * s + w;
#pragma unroll
      for (int kc = 0; kc < 16; ++kc) {
        h8v av = *(const h8v*)(arow + kc * 32);
        z0 = __builtin_amdgcn_mfma_f32_16x16x32_f16(av, wt[(size_t)((0 * 32 + tb) * 18 + kc) * 64 + lane], z0, 0, 0, 0);
        z1 = __builtin_amdgcn_mfma_f32_16x16x32_f16(av, wt[(size_t)((1 * 32 + tb) * 18 + kc) * 64 + lane], z1, 0, 0, 0);
        z2 = __builtin_amdgcn_mfma_f32_16x16x32_f16(av, wt[(size_t)((2 * 32 + tb) * 18 + kc) * 64 + lane], z2, 0, 0, 0);
        z3 = __builtin_amdgcn_mfma_f32_16x16x32_f16(av, wt[(size_t)((3 * 32 + tb) * 18 + kc) * 64 + lane], z3, 0, 0, 0);
      }
      const float* xr = x + ((size_t)(c * 16 + lm) * T_ + ts) * IN_ + quad * 8;
#pragma unroll
      for (int kx = 0; kx < 2; ++kx) {
        float4 f0 = *(const float4*)(xr + kx * 32);
        float4 f1 = *(const float4*)(xr + kx * 32 + 4);
        h8v av;
        av[0] = (_Float16)f0.x; av[1] = (_Float16)f0.y; av[2] = (_Float16)f0.z; av[3] = (_Float16)f0.w;
        av[4] = (_Float16)f1.x; av[5] = (_Float16)f1.y; av[6] = (_Float16)f1.z; av[7] = (_Float16)f1.w;
        int kc = 16 + kx;
        z0 = __builtin_amdgcn_mfma_f32_16x16x32_f16(av, wt[(size_t)((0 * 32 + tb) * 18 + kc) * 64 + lane], z0, 0, 0, 0);
        z1 = __builtin_amdgcn_mfma_f32_16x16x32_f16(av, wt[(size_t)((1 * 32 + tb) * 18 + kc) * 64 + lane], z1, 0, 0, 0);
        z2 = __builtin_amdgcn_mfma_f32_16x16x32_f16(av, wt[(size_t)((2 * 32 + tb) * 18 + kc) * 64 + lane], z2, 0, 0, 0);
        z3 = __builtin_amdgcn_mfma_f32_16x16x32_f16(av, wt[(size_t)((3 * 32 + tb) * 18 + kc) * 64 + lane], z3, 0, 0, 0);
      }
      __syncthreads();                    // all waves done reading ACT (h_prev)
#pragma unroll
      for (int r = 0; r < 4; ++r) {
        float zi = z0[r] + zb0, zf = z1[r] + zb1, zg = z2[r] + zb2, zo = z3[r] + zb3;
        float cv = fsigm(zf) * c_[r] + fsigm(zi) * ftanh(zg);
        c_[r] = cv;
        h_[r] = fsigm(zo) * ftanh(cv);
        ACT[(quad * 4 + r) * LD_ + col] = (_Float16)h_[r];
      }
    }
    ++phase;
    phase_exchange(cnt, Xchg + (size_t)((phase & 1) * 16 + c) * 2048, ACT, s, 8 * phase);

    // ---- P2: u1 = h·W1^T + b1 ----
    {
      f4v D = mm_lds(ACT, W1s, w, lane);
      __syncthreads();
#pragma unroll
      for (int r = 0; r < 4; ++r) {
        float uv = D[r] + b1r;
        u1a[r] = uv;
        float t1v = ftanh(uv);
        SSa[r] = t1v;
        ACT[(quad * 4 + r) * LD_ + col] = (_Float16)t1v;
      }
    }
    ++phase;
    phase_exchange(cnt, Xchg + (size_t)((phase & 1) * 16 + c) * 2048, ACT, s, 8 * phase);

    // ---- 3 RK4 unfolds in u-space (M in VGPRs) ----
#pragma unroll 1
    for (int uf = 0; uf < 3; ++uf) {
      {
        f4v D = mm_reg(ACT, mreg, lane);
        __syncthreads();
#pragma unroll
        for (int r = 0; r < 4; ++r) {
          float Dv = D[r];
          float u2 = u1a[r] + 0.5f * dt_[r] * (Dv + dvr);
          SMa[r] = Dv;
          float t2v = ftanh(u2);
          SSa[r] += 2.0f * t2v;
          ACT[(quad * 4 + r) * LD_ + col] = (_Float16)t2v;
        }
      }
      ++phase;
      phase_exchange(cnt, Xchg + (size_t)((phase & 1) * 16 + c) * 2048, ACT, s, 8 * phase);

      {
        f4v D = mm_reg(ACT, mreg, lane);
        __syncthreads();
#pragma unroll
        for (int r = 0; r < 4; ++r) {
          float Dv = D[r];
          float u3 = u1a[r] + 0.5f * dt_[r] * (Dv + dvr);
          SMa[r] += 2.0f * Dv;
          float t3v = ftanh(u3);
          SSa[r] += 2.0f * t3v;
          ACT[(quad * 4 + r) * LD_ + col] = (_Float16)t3v;
        }
      }
      ++phase;
      phase_exchange(cnt, Xchg + (size_t)((phase & 1) * 16 + c) * 2048, ACT, s, 8 * phase);

      {
        f4v D = mm_reg(ACT, mreg, lane);
        __syncthreads();
#pragma unroll
        for (int r = 0; r < 4; ++r) {
          float Dv = D[r];
          float u4 = u1a[r] + dt_[r] * (Dv + dvr);
          SMa[r] += 2.0f * Dv;
          float t4v = ftanh(u4);
          SSa[r] += t4v;
          ACT[(quad * 4 + r) * LD_ + col] = (uf < 2) ? (_Float16)t4v : (_Float16)SSa[r];
        }
      }
      ++phase;
      phase_exchange(cnt, Xchg + (size_t)((phase & 1) * 16 + c) * 2048, ACT, s, 8 * phase);

      if (uf < 2) {
        f4v D = mm_reg(ACT, mreg, lane);
        __syncthreads();
#pragma unroll
        for (int r = 0; r < 4; ++r) {
          float Dv = D[r];
          SMa[r] += Dv;
          float un = u1a[r] + (dt_[r] * (1.0f / 6.0f)) * SMa[r] + dt_[r] * dvr;
          u1a[r] = un;
          float t1v = ftanh(un);
          SSa[r] += t1v;
          ACT[(quad * 4 + r) * LD_ + col] = (_Float16)t1v;
        }
        ++phase;
        phase_exchange(cnt, Xchg + (size_t)((phase & 1) * 16 + c) * 2048, ACT, s, 8 * phase);
      }
    }

    // ---- P_h: h += (dt/6)·(S_tot·W2^T) + 3dt·b2 ; publish h + Hsave ----
    {
      f4v D = mm_lds(ACT, W2s, w, lane);
      __syncthreads();
#pragma unroll
      for (int r = 0; r < 4; ++r) {
        h_[r] += (dt_[r] * (1.0f / 6.0f)) * D[r] + (3.0f * dt_[r]) * b2r;
        _Float16 hv = (_Float16)h_[r];
        ACT[(quad * 4 + r) * LD_ + col] = hv;
        Hsave[((size_t)(ts + 1) * B_ + c * 16 + quad * 4 + r) * H_ + col] = hv;
      }
    }
    ++phase;
    phase_exchange(cnt, Xchg + (size_t)((phase & 1) * 16 + c) * 2048, ACT, s, 8 * phase);
  }
}

// ---------------- final projection: out = h·Wco^T + bprime ----------------
__global__ void final_out(const _Float16* __restrict__ Hsave,
                          const float* __restrict__ Wco,
                          const float* __restrict__ bprime,
                          float* __restrict__ out) {
  __shared__ float wcs[NC_][520];
  int tid = threadIdx.x;
  for (int i = tid; i < NC_ * 512; i += 256) wcs[i >> 9][i & 511] = Wco[i];
  __syncthreads();
  int r0 = blockIdx.x * 64;
  int rl = tid >> 4, cc = tid & 15;
  for (int pass = 0; pass < 4; ++pass) {
    int row = r0 + pass * 16 + rl;        // row = b*T + t
    int b = row >> 7, t = row & 127;
    const _Float16* hrow = Hsave + ((size_t)(t + 1) * B_ + b) * H_;
    if (cc < NC_) {
      float acc = 0.f;
      for (int k8 = 0; k8 < 64; ++k8) {
        h8v hv = *(const h8v*)(hrow + k8 * 8);
#pragma unroll
        for (int j = 0; j < 8; ++j) acc += (float)hv[j] * wcs[cc][k8 * 8 + j];
      }
      out[(size_t)row * NC_ + cc] = acc + bprime[cc];
    }
  }
}

extern "C" void kernel_launch(void* const* d_in, const int* in_sizes, int n_in,
                              void* d_out, int out_size, void* d_ws, size_t ws_size,
                              hipStream_t stream) {
  (void)in_sizes; (void)n_in; (void)out_size; (void)ws_size;
  const float* x   = (const float*)d_in[0];
  const float* tin = (const float*)d_in[1];
  const float* Wih = (const float*)d_in[2];
  const float* Whh = (const float*)d_in[3];
  const float* bih = (const float*)d_in[4];
  const float* bhh = (const float*)d_in[5];
  const float* W1  = (const float*)d_in[6];
  const float* b1  = (const float*)d_in[7];
  const float* W2  = (const float*)d_in[8];
  const float* b2  = (const float*)d_in[9];
  const float* Wo  = (const float*)d_in[10];
  const float* bo  = (const float*)d_in[11];
  const float* Wc  = (const float*)d_in[12];
  const float* bc  = (const float*)d_in[13];

  char* ws = (char*)d_ws;
  size_t off = 0;
  auto alloc = [&](size_t bytes) -> void* {
    void* p = ws + off;
    off = (off + bytes + 1023) & ~(size_t)1023;
    return p;
  };
  _Float16* Wtil  = (_Float16*)alloc((size_t)2304 * 512 * 2);
  _Float16* W1T   = (_Float16*)alloc((size_t)512 * 512 * 2);
  _Float16* W2T   = (_Float16*)alloc((size_t)512 * 512 * 2);
  _Float16* MF    = (_Float16*)alloc((size_t)512 * 512 * 2);
  float*    Mtmp  = (float*)alloc((size_t)512 * 512 * 4);
  float*    dvec  = (float*)alloc(512 * 4);
  float*    WcoF  = (float*)alloc((size_t)NC_ * 512 * 4);
  float*    bprim = (float*)alloc(64);
  _Float16* Hsave = (_Float16*)alloc((size_t)(T_ + 1) * B_ * H_ * 2);
  ull*      Xchg  = (ull*)alloc((size_t)2 * 16 * 2048 * 8);
  int*      flags = (int*)alloc(16 * 32 * 4);

  hipMemsetAsync(flags, 0, 16 * 32 * 4, stream);

  prep_M<<<64, 256, 0, stream>>>(W1, W2, Mtmp);
  prep_small<<<4, 256, 0, stream>>>(W1, b2, Wc, Wo, bo, bc, dvec, WcoF, bprim);
  prep_wtilde<<<576, 256, 0, stream>>>(Whh, Wih, Wtil);
  prep_fragW<<<128, 256, 0, stream>>>(W1, W1T);
  prep_fragW<<<128, 256, 0, stream>>>(W2, W2T);
  prep_fragM<<<128, 256, 0, stream>>>(Mtmp, MF);
  recur<<<128, 256, 0, stream>>>(x, tin, bih, bhh, b1, b2, Wtil, W1T, W2T, MF,
                                 dvec, Hsave, Xchg, flags);
  final_out<<<512, 256, 0, stream>>>(Hsave, WcoF, bprim, (float*)d_out);
}